// Round 17
// baseline (268.096 us; speedup 1.0000x reference)
//
#include <hip/hip_runtime.h>
#include <hip/hip_bf16.h>

#define N_NODES 50000
#define N_EDGES 800000
#define IN_DIM 64
#define HID_DIM 128
#define OUT_DIM 64
#define NGRP 8
#define NSLC 4                                // feature slices (16 floats = 64B line)
#define NPB 64                                // nodes per agg block (16/wave x 4 waves)
#define ECAP 2048                             // staged edge cap per block
#define NE8 (NGRP * N_NODES)                  // 400000
#define NC8C ((NE8 + 255) / 256)              // 1563 scan chunks (group-major)
#define NCMC ((N_NODES + 255) / 256)          // 196 scan chunks (merged)

// ---- device-global scratch (zero-initialized at module load; deg8 re-zeroed
//      by addoffs after its last use each iteration) ----
__device__ int g_in_f32;
__device__ int g_is64;
__device__ int g_csr[N_EDGES];                // group-major partitioned CSR
__device__ int g_mcsr[N_EDGES];               // merged node-major CSR
__device__ int g_deg8[NE8];                   // [g][v]
__device__ int g_rowptr8[NE8 + 1];
__device__ int g_cursor8[NE8];
__device__ int g_mrp[N_NODES + 1];
__device__ int g_bsum[NC8C];
__device__ int g_bsum2[NCMC];
__device__ float g_dinv[N_NODES];
__device__ __align__(16) float g_W1f[IN_DIM * HID_DIM];
__device__ __align__(16) float g_W2f[HID_DIM * OUT_DIM];
__device__ __align__(16) float g_b1f[HID_DIM];
__device__ __align__(16) float g_b2f[OUT_DIM];
// g_hs1: aggz out blocked [4][N][16]; then hs2 blocked [4][N][16] (in-place per-row swap in gemm_fused)
__device__ __align__(16) float g_hs1[(size_t)N_NODES * IN_DIM];
// g_agg1: zb blocked [4][N][16] (dinv-scaled z)
__device__ __align__(16) float g_agg1[(size_t)N_NODES * IN_DIM];

__device__ __forceinline__ float loadx(const void* p, int i, int f32) {
    if (f32) return ((const float*)p)[i];
    unsigned int u = ((unsigned int)((const unsigned short*)p)[i]) << 16;
    return __uint_as_float(u);
}

// ---- K1: per-group degree count + detect ----
// per-block is64 detect: TWO coalesced 64-word windows of consecutive ODD words at
// block-dependent offsets (~16 cache lines/block). int64 idx < 2^32 -> all odd words
// zero (exact); int32 -> 128 node ids all zero is P~0. Block 0 publishes flags.
// deg8 is zero on entry: .bss init on first run, addoffs re-zeroes each iteration.
__global__ __launch_bounds__(256) void degprep_kernel(const void* __restrict__ ei,
                                                      const unsigned short* __restrict__ zw,
                                                      int N, int E) {
    __shared__ int s_nz, s_f32;
    int t = threadIdx.x;
    if (t == 0) { s_nz = 0; s_f32 = 0; }
    __syncthreads();
    const unsigned int* ew = (const unsigned int*)ei;
    if (t < 128) {
        int win = t >> 6;                     // two windows per block
        int lane = t & 63;
        long long seed = (long long)blockIdx.x * (win ? 48611 : 12347) + win * 131071;
        int base = (int)(seed % (long long)(E - 64));
        if (ew[1 + 2 * (base + lane)] != 0) atomicOr(&s_nz, 1);
    }
    if (blockIdx.x == 0) {
        // robust f32 detect (16K samples), published for downstream kernels
        int hit = 0;
        for (int k = 0; k < 64; k++) {
            int i = 2 * ((t * 64 + k) * 97);
            if (((zw[i] >> 7) & 0xFF) == 0xFF) hit = 1;
        }
        if (hit) atomicOr(&s_f32, 1);
    }
    __syncthreads();
    int is64 = (s_nz == 0);
    if (blockIdx.x == 0 && t == 0) { g_in_f32 = s_f32; g_is64 = is64; }
    int e = blockIdx.x * 256 + t;
    if (e < E) {
        int d = is64 ? (int)((const long long*)ei)[E + e] : ((const int*)ei)[E + e];
        int g = blockIdx.x & (NGRP - 1);          // round-robin -> XCD-local counters
        atomicAdd(&g_deg8[g * N + d], 1);
    }
}

// ---- K2: chunk-local scans ONLY (no fences, no cross-block ordering) ----
__global__ __launch_bounds__(256) void scans_kernel(int N, int NE) {
    __shared__ int sc[256];
    int t = threadIdx.x;
    int NC8 = (NE + 255) >> 8, NCM = (N + 255) >> 8;
    for (int vb = blockIdx.x; vb < NC8; vb += gridDim.x) {
        int idx = (vb << 8) + t;
        int d = (idx < NE) ? g_deg8[idx] : 0;
        sc[t] = d;
        __syncthreads();
        for (int off = 1; off < 256; off <<= 1) {
            int v = (t >= off) ? sc[t - off] : 0;
            __syncthreads();
            sc[t] += v;
            __syncthreads();
        }
        if (idx < NE) g_rowptr8[idx] = sc[t] - d;  // local exclusive prefix
        if (t == 255) g_bsum[vb] = sc[255];
        __syncthreads();
    }
    for (int vb = blockIdx.x; vb < NCM; vb += gridDim.x) {
        int idx = (vb << 8) + t;
        int d = 0;
        if (idx < N) {
#pragma unroll
            for (int g = 0; g < NGRP; g++) d += g_deg8[g * N + idx];
            g_dinv[idx] = rsqrtf((float)d + 1.0f);  // +1 = self loop
        }
        sc[t] = d;
        __syncthreads();
        for (int off = 1; off < 256; off <<= 1) {
            int v = (t >= off) ? sc[t - off] : 0;
            __syncthreads();
            sc[t] += v;
            __syncthreads();
        }
        if (idx < N) g_mrp[idx] = sc[t] - d;
        if (t == 255) g_bsum2[vb] = sc[255];
        __syncthreads();
    }
}

// ---- K3: per-block prefix over bsum (L2-hot) + add offsets + deg8 self-clean ----
// reads of g_bsum/g_bsum2 are ordered by the kernel boundary -> no fences needed;
// deg8 is dead after scans, so zeroing here leaves it clean for the next replay.
__global__ __launch_bounds__(256) void addoffs_kernel(int N, int NE, int E) {
    __shared__ int sc[256];
    int t = threadIdx.x;
    int vb = blockIdx.x;
    int NCM = (N + 255) >> 8;
    int ps = 0;
    for (int i = t; i < vb; i += 256) ps += g_bsum[i];
    sc[t] = ps;
    __syncthreads();
    for (int off = 128; off > 0; off >>= 1) {
        if (t < off) sc[t] += sc[t + off];
        __syncthreads();
    }
    int prefix = sc[0];
    __syncthreads();
    int idx = vb * 256 + t;
    if (idx < NE) {
        int base = g_rowptr8[idx] + prefix;
        g_rowptr8[idx] = base;
        g_cursor8[idx] = base;
        g_deg8[idx] = 0;                      // self-clean for next iteration
    }
    if (vb < NCM) {
        int ps2 = 0;
        for (int i = t; i < vb; i += 256) ps2 += g_bsum2[i];
        sc[t] = ps2;
        __syncthreads();
        for (int off = 128; off > 0; off >>= 1) {
            if (t < off) sc[t] += sc[t + off];
            __syncthreads();
        }
        int prefix2 = sc[0];
        if (idx < N) g_mrp[idx] += prefix2;
    }
    if (vb == 0 && t == 0) { g_rowptr8[NE] = E; g_mrp[N] = E; }
}

// ---- K4: scatter edges into group-partitioned CSR (src/dst direct from ei) ----
__global__ __launch_bounds__(256) void scatter_kernel(const void* __restrict__ ei, int N, int E) {
    int e = blockIdx.x * 256 + threadIdx.x;
    if (e < E) {
        int s, d;
        if (g_is64) { const long long* p = (const long long*)ei; s = (int)p[e]; d = (int)p[E + e]; }
        else        { const int* p = (const int*)ei; s = p[e]; d = p[E + e]; }
        int g = blockIdx.x & (NGRP - 1);
        int pos = atomicAdd(&g_cursor8[g * N + d], 1);
        if (pos < E) g_csr[pos] = s;          // guard vs corrupted replay state
    }
}

// ---- K5: merge group CSR -> node-major mcsr (wave/node) + zprep blocked + W/b f32 prep ----
__global__ __launch_bounds__(256) void mergezp_kernel(const void* __restrict__ z,
                                                      const void* __restrict__ W1, const void* __restrict__ b1,
                                                      const void* __restrict__ W2, const void* __restrict__ b2,
                                                      int N) {
    int gid = blockIdx.x * 256 + threadIdx.x;
    int f32 = g_in_f32;
    if (gid < IN_DIM * HID_DIM) g_W1f[gid] = loadx(W1, gid, f32);
    if (gid < HID_DIM * OUT_DIM) g_W2f[gid] = loadx(W2, gid, f32);
    if (gid < HID_DIM) g_b1f[gid] = loadx(b1, gid, f32);
    if (gid < OUT_DIM) g_b2f[gid] = loadx(b2, gid, f32);
    int wid = gid >> 6;
    int lane = threadIdx.x & 63;
    if (wid < N) {
        int mybeg = 0, mycnt = 0;
        if (lane < NGRP) {
            mybeg = g_rowptr8[lane * N + wid];
            mycnt = g_rowptr8[lane * N + wid + 1] - mybeg;
        }
        int incl = mycnt;
#pragma unroll
        for (int off = 1; off < NGRP; off <<= 1) {
            int v = __shfl_up(incl, off, 64);
            if (lane >= off) incl += v;
        }
        int myoff = incl - mycnt;
        int go[NGRP], gb[NGRP];
#pragma unroll
        for (int k = 0; k < NGRP; k++) {
            go[k] = __shfl(myoff, k, 64);
            gb[k] = __shfl(mybeg, k, 64);
        }
        int total = __shfl(incl, NGRP - 1, 64);
        int base = g_mrp[wid];
        for (int i = lane; i < total; i += 64) {
            int g = 0;
#pragma unroll
            for (int k = 1; k < NGRP; k++) g += (i >= go[k]);
            g_mcsr[base + i] = g_csr[gb[g] + i - go[g]];
        }
    }
    if (gid < N * IN_DIM) {
        int node = gid >> 6, c = gid & 63;
        int s = c >> 4, off = c & 15;
        g_agg1[(size_t)s * (N * 16) + node * 16 + off] = loadx(z, gid, f32) * g_dinv[node];
    }
}

// ---- K6/K8: lane-per-(node,col4) sliced aggregation: 64 nodes x 1 slice per block ----
// lane = (node 0..15, col4 0..3): serial float4 gather per lane -> NO cross-lane
// reduce, b128 loads (16 rows/instr/wave), ~0.5 issue/edge.
// slice pinned via blockIdx&3 -> per-XCD 3.2MB table stays L2-resident.
template <int LAYER2>
__global__ __launch_bounds__(256) void aggslc_kernel(void* __restrict__ outp, int N) {
    __shared__ int rp[NPB + 1];
    __shared__ int eidx[ECAP];
    int s = blockIdx.x & (NSLC - 1);
    int n0 = (blockIdx.x >> 2) * NPB;
    int t = threadIdx.x;
    if (t <= NPB) {
        int idx = n0 + t;
        rp[t] = g_mrp[idx <= N ? idx : N];
    }
    __syncthreads();
    int base = rp[0];
    int range = rp[NPB] - base;
    bool staged = (range <= ECAP);
    if (staged) {
        for (int i = t; i < range; i += 256) eidx[i] = g_mcsr[base + i];
    }
    __syncthreads();
    const float* tab = (LAYER2 ? g_hs1 : g_agg1) + (size_t)s * ((size_t)N * 16);
    int lane = t & 63;
    int nsub = (t >> 6) * 16 + (lane >> 2);   // node index within block (0..63)
    int col4 = lane & 3;                      // float4 column (4 lanes per node)
    int nk = n0 + nsub;
    if (nk >= N) return;
    float4 a0 = make_float4(0.f, 0.f, 0.f, 0.f);
    float4 a1 = make_float4(0.f, 0.f, 0.f, 0.f);
    int jb = rp[nsub] - base;
    int je = rp[nsub + 1] - base;
    if (staged) {
        int j = jb;
        for (; j + 1 < je; j += 2) {
            int i0 = eidx[j], i1 = eidx[j + 1];
            float4 v0 = *(const float4*)&tab[(size_t)i0 * 16 + col4 * 4];
            float4 v1 = *(const float4*)&tab[(size_t)i1 * 16 + col4 * 4];
            a0.x += v0.x; a0.y += v0.y; a0.z += v0.z; a0.w += v0.w;
            a1.x += v1.x; a1.y += v1.y; a1.z += v1.z; a1.w += v1.w;
        }
        if (j < je) {
            float4 v0 = *(const float4*)&tab[(size_t)eidx[j] * 16 + col4 * 4];
            a0.x += v0.x; a0.y += v0.y; a0.z += v0.z; a0.w += v0.w;
        }
    } else {  // essentially-never fallback: direct global index walk
        for (int j = jb; j < je; j++) {
            float4 v0 = *(const float4*)&tab[(size_t)g_mcsr[base + j] * 16 + col4 * 4];
            a0.x += v0.x; a0.y += v0.y; a0.z += v0.z; a0.w += v0.w;
        }
    }
    float4 self = *(const float4*)&tab[(size_t)nk * 16 + col4 * 4];
    float dn = g_dinv[nk];
    float4 v;
    v.x = (a0.x + a1.x + self.x) * dn;
    v.y = (a0.y + a1.y + self.y) * dn;
    v.z = (a0.z + a1.z + self.z) * dn;
    v.w = (a0.w + a1.w + self.w) * dn;
    if (LAYER2) {
        float4 bias = *(const float4*)&g_b2f[s * 16 + col4 * 4];
        v.x += bias.x; v.y += bias.y; v.z += bias.z; v.w += bias.w;
        int oc = nk * 64 + s * 16 + col4 * 4;
        if (g_in_f32) {
            *(float4*)&((float*)outp)[oc] = v;
        } else {
            __hip_bfloat16* o = (__hip_bfloat16*)outp + oc;
            o[0] = __float2bfloat16(v.x);
            o[1] = __float2bfloat16(v.y);
            o[2] = __float2bfloat16(v.z);
            o[3] = __float2bfloat16(v.w);
        }
    } else {
        *(float4*)&g_hs1[(size_t)s * ((size_t)N * 16) + nk * 16 + col4 * 4] = v;
    }
}

// ---- K7: FUSED MLP per 64-row block: hs2 = (relu(aggz@W1+b1))@W2 * dinv ----
// 64 rows/block doubles FMA per W-load / LDS-load: gemm1 = 32 FMA/thread/k-iter,
// gemm2 = 64 FMA/thread/k4-iter -> latency chains covered by ILP.
// Single UNION LDS buffer [64][132] (33.8 KB): input (k<64) during gemm1, then h (k<128).
__global__ __launch_bounds__(256) void gemm_fused_kernel(int N) {
    __shared__ __align__(16) float B[64 * 132];   // 33792 B
    int t = threadIdx.x;
    int row0 = blockIdx.x * 64;
    // stage aggz (blocked [4][N][16]) row-major into B: 1024 float4 = 4/thread
#pragma unroll
    for (int s = 0; s < 4; s++) {
        int i = t + s * 256;
        int r = i >> 4, k4 = i & 15;
        int row = row0 + r;
        int g = k4 >> 2, off = (k4 & 3) * 4;
        float4 v = make_float4(0.f, 0.f, 0.f, 0.f);
        if (row < N) v = *(const float4*)&g_hs1[(size_t)g * (N * 16) + row * 16 + off];
        *(float4*)&B[r * 132 + k4 * 4] = v;
    }
    __syncthreads();
    // gemm1: 32 colgroups x 8 rowgroups, 8x4 micro-tile -> registers
    int cg1 = t & 31, rg1 = t >> 5;
    int c1 = cg1 * 4, r1 = rg1 * 8;
    float acc1[8][4] = {};
#pragma unroll 4
    for (int k = 0; k < IN_DIM; k++) {
        float b[4];
        *(float4*)b = *(const float4*)&g_W1f[k * HID_DIM + c1];
        float a[8];
#pragma unroll
        for (int i = 0; i < 8; i++) a[i] = B[(r1 + i) * 132 + k];
#pragma unroll
        for (int i = 0; i < 8; i++)
#pragma unroll
            for (int j = 0; j < 4; j++) acc1[i][j] = fmaf(a[i], b[j], acc1[i][j]);
    }
    __syncthreads();   // all input reads complete before h overwrites the buffer
    {
        float4 bias = *(const float4*)&g_b1f[c1];
#pragma unroll
        for (int i = 0; i < 8; i++) {
            float4 v;
            v.x = fmaxf(acc1[i][0] + bias.x, 0.f);
            v.y = fmaxf(acc1[i][1] + bias.y, 0.f);
            v.z = fmaxf(acc1[i][2] + bias.z, 0.f);
            v.w = fmaxf(acc1[i][3] + bias.w, 0.f);
            *(float4*)&B[(r1 + i) * 132 + c1] = v;
        }
    }
    __syncthreads();
    // gemm2: 16 colgroups x 16 rowgroups, 4x4 micro-tile; K=128 via float4 chunks of B
    {
        int cg = t & 15, rg = t >> 4;
        int c0 = cg * 4, r0 = rg * 4;
        float acc[4][4] = {};
#pragma unroll 2
        for (int k4 = 0; k4 < 32; k4++) {
            float av[4][4];
#pragma unroll
            for (int i = 0; i < 4; i++)
                *(float4*)av[i] = *(const float4*)&B[(r0 + i) * 132 + k4 * 4];
#pragma unroll
            for (int jj = 0; jj < 4; jj++) {
                float b[4];
                *(float4*)b = *(const float4*)&g_W2f[(k4 * 4 + jj) * OUT_DIM + c0];
#pragma unroll
                for (int i = 0; i < 4; i++)
#pragma unroll
                    for (int j = 0; j < 4; j++) acc[i][j] = fmaf(av[i][jj], b[j], acc[i][j]);
            }
        }
        int g = cg >> 2, off = (cg & 3) * 4;  // blocked output [4][N][16]
#pragma unroll
        for (int i = 0; i < 4; i++) {
            int row = row0 + r0 + i;
            if (row < N) {
                float dn = g_dinv[row];
                float4 v;
                v.x = acc[i][0] * dn;
                v.y = acc[i][1] * dn;
                v.z = acc[i][2] * dn;
                v.w = acc[i][3] * dn;
                *(float4*)&g_hs1[(size_t)g * (N * 16) + row * 16 + off] = v;
            }
        }
    }
}

extern "C" void kernel_launch(void* const* d_in, const int* in_sizes, int n_in,
                              void* d_out, int out_size, void* d_ws, size_t ws_size,
                              hipStream_t stream) {
    const void* z  = d_in[0];
    const void* ei = d_in[1];
    const void* W1 = d_in[2];
    const void* b1 = d_in[3];
    const void* W2 = d_in[4];
    const void* b2 = d_in[5];

    const int N = in_sizes[0] / IN_DIM;  // 50000
    const int E = in_sizes[1] / 2;       // 800000
    const int NE = NGRP * N;             // 400000
    const int NC8 = (NE + 255) / 256;    // 1563
    const int aggblocks = NSLC * ((N + NPB - 1) / NPB);  // 3128

    degprep_kernel<<<(E + 255) / 256, 256, 0, stream>>>(ei, (const unsigned short*)z, N, E);
    scans_kernel<<<NC8, 256, 0, stream>>>(N, NE);
    addoffs_kernel<<<NC8, 256, 0, stream>>>(N, NE, E);
    scatter_kernel<<<(E + 255) / 256, 256, 0, stream>>>(ei, N, E);
    mergezp_kernel<<<(N * 64 + 255) / 256, 256, 0, stream>>>(z, W1, b1, W2, b2, N);

    aggslc_kernel<0><<<aggblocks, 256, 0, stream>>>(d_out, N);
    gemm_fused_kernel<<<(N + 63) / 64, 256, 0, stream>>>(N);
    aggslc_kernel<1><<<aggblocks, 256, 0, stream>>>(d_out, N);
}